// Round 12
// baseline (431.014 us; speedup 1.0000x reference)
//
#include <hip/hip_runtime.h>
#include <hip/hip_bf16.h>

#define N_NODES 150000
#define CDIM 256
#define DIM 256
#define BM 32
#define NT 4688          // ceil(150000/32)
#define GRID 1024        // persistent blocks, 4 per CU

typedef float f32x4 __attribute__((ext_vector_type(4)));
typedef short bf16x8 __attribute__((ext_vector_type(8)));
typedef unsigned short u16x8 __attribute__((ext_vector_type(8)));

// ws layout (bytes)
#define WS_CB 0          // bf16 B fragments: [32][256][8] ushort = 131072 B
#define WS_SC 131072     // sc[256] f32
#define WS_RC2 132096    // rc2[256] = 2/(1-sc) f32
#define WS_MSUM 133120   // masksum[1] f32
#define WS_GACCR 133632  // gaccR[64][256] f32 = 65536 B
#define WS_ZERO_FROM 133120
#define WS_ZERO_LEN (133632 + 65536 - 133120)

__device__ __forceinline__ unsigned short f2bf(float f) {
  unsigned u = __float_as_uint(f);
  u += 0x7FFFu + ((u >> 16) & 1u);   // round-to-nearest-even
  return (unsigned short)(u >> 16);
}

// blocks 0..255: centroid row b -> bf16 frag layout + sc[b] + rc2[b]
// blocks 256..319: grid-stride sum of mask -> msum
__global__ void cd_prep(const float* __restrict__ cw, const float* __restrict__ mask,
                        unsigned short* __restrict__ cb, float* __restrict__ sc,
                        float* __restrict__ rc2, float* __restrict__ msum) {
  int b = blockIdx.x;
  int t = threadIdx.x;
  int wave = t >> 6, lane = t & 63;
  __shared__ float red[4];
  if (b < CDIM) {
    float v = cw[b * DIM + t];
    cb[(size_t)(t >> 3) * (CDIM * 8) + b * 8 + (t & 7)] = f2bf(v);
    float ss = v * v;
    #pragma unroll
    for (int off = 32; off >= 1; off >>= 1) ss += __shfl_xor(ss, off);
    if (lane == 0) red[wave] = ss;
    __syncthreads();
    if (t == 0) {
      float s = red[0] + red[1] + red[2] + red[3];
      sc[b] = s;
      rc2[b] = 2.0f / (1.0f - s);
    }
  } else {
    int idx = (b - CDIM) * 256 + t;
    const int stride = 64 * 256;
    float s = 0.f;
    for (int i = idx; i < N_NODES; i += stride) s += mask[i];
    #pragma unroll
    for (int off = 32; off >= 1; off >>= 1) s += __shfl_xor(s, off);
    if (lane == 0) red[wave] = s;
    __syncthreads();
    if (t == 0) atomicAdd(msum, red[0] + red[1] + red[2] + red[3]);
  }
}

__global__ __launch_bounds__(256, 4)
void cd_main(const float* __restrict__ x, const float* __restrict__ mask,
             const unsigned short* __restrict__ cb, const float* __restrict__ sc,
             const float* __restrict__ rc2, float* __restrict__ gaccR,
             float* __restrict__ out1) {
  // A-tile [kf(32)][row(32)][8] bf16, XOR-swizzled: byte ^= (kf&7)<<4.
  // Staging write (16B/thread): bank-group m = (srow&7)^sub -> 8 lanes each,
  // 8 rounds = floor. Frag read (b128): m = (ln&7)^(kf&7) -> 8 rounds = floor.
  __shared__ unsigned short ab[32 * BM * 8];
  __shared__ float sxl[BM];
  __shared__ float mskl[BM];

  const int t = threadIdx.x;
  const int bid = blockIdx.x;
  const int lane = t & 63;
  const int w = t >> 6;
  const int q = lane >> 4;
  const int ln = lane & 15;
  const int c0 = w * 64;
  const int srow = t >> 3;     // staging row 0..31
  const int sub  = t & 7;      // staging col-group 0..7

  f32x4 va[4], vb[4];
  float mreg;

  // ---- prologue: load tile `bid` into regs, then LDS ----
  {
    long grow = (long)bid * BM + srow;
    bool ok = grow < N_NODES;
    const float* px = x + grow * DIM + sub * 8;
    #pragma unroll
    for (int i = 0; i < 4; ++i) {
      va[i] = ok ? *(const f32x4*)(px + i * 64) : f32x4{0.f, 0.f, 0.f, 0.f};
      vb[i] = ok ? *(const f32x4*)(px + i * 64 + 4) : f32x4{0.f, 0.f, 0.f, 0.f};
    }
    mreg = ok ? mask[grow] : 0.f;
  }
  {
    float ss = 0.f;
    #pragma unroll
    for (int i = 0; i < 4; ++i) {
      ss = fmaf(va[i].x, va[i].x, ss); ss = fmaf(va[i].y, va[i].y, ss);
      ss = fmaf(va[i].z, va[i].z, ss); ss = fmaf(va[i].w, va[i].w, ss);
      ss = fmaf(vb[i].x, vb[i].x, ss); ss = fmaf(vb[i].y, vb[i].y, ss);
      ss = fmaf(vb[i].z, vb[i].z, ss); ss = fmaf(vb[i].w, vb[i].w, ss);
      u16x8 bpk;
      bpk[0] = f2bf(va[i].x); bpk[1] = f2bf(va[i].y);
      bpk[2] = f2bf(va[i].z); bpk[3] = f2bf(va[i].w);
      bpk[4] = f2bf(vb[i].x); bpk[5] = f2bf(vb[i].y);
      bpk[6] = f2bf(vb[i].z); bpk[7] = f2bf(vb[i].w);
      const int kf = sub + 8 * i;
      *(u16x8*)(ab + (((kf * BM + srow) * 8) ^ (sub << 3))) = bpk;
    }
    ss += __shfl_xor(ss, 1);
    ss += __shfl_xor(ss, 2);
    ss += __shfl_xor(ss, 4);
    if (sub == 0) { sxl[srow] = ss; mskl[srow] = mreg; }
  }
  __syncthreads();

  // loop-invariant per-column terms
  float scv[4], rc2v[4];
  #pragma unroll
  for (int nt = 0; nt < 4; ++nt) {
    scv[nt] = sc[c0 + nt * 16 + ln];
    rc2v[nt] = rc2[c0 + nt * 16 + ln];
  }

  float pc[4] = {0.f, 0.f, 0.f, 0.f};

  for (long tt = bid; tt < NT; tt += GRID) {
    const long tn = tt + GRID;
    const bool have_next = tn < NT;

    // ---- MFMA over current A-tile, pipelined B loads from L2 ----
    f32x4 acc[2][4] = {};
    bf16x8 bfc[4], bfn[4];
    #pragma unroll
    for (int nt = 0; nt < 4; ++nt)
      bfc[nt] = *(const bf16x8*)(cb + (size_t)q * (CDIM * 8) + (c0 + nt * 16 + ln) * 8);
    #pragma unroll
    for (int kt = 0; kt < 8; ++kt) {
      if (kt < 7) {
        #pragma unroll
        for (int nt = 0; nt < 4; ++nt)
          bfn[nt] = *(const bf16x8*)(cb + (size_t)((kt + 1) * 4 + q) * (CDIM * 8) + (c0 + nt * 16 + ln) * 8);
      }
      const int kf = kt * 4 + q;
      bf16x8 af0 = *(const bf16x8*)(ab + (((kf * BM + ln) * 8) ^ ((kf & 7) << 3)));
      bf16x8 af1 = *(const bf16x8*)(ab + (((kf * BM + 16 + ln) * 8) ^ ((kf & 7) << 3)));
      #pragma unroll
      for (int nt = 0; nt < 4; ++nt)
        acc[0][nt] = __builtin_amdgcn_mfma_f32_16x16x32_bf16(af0, bfc[nt], acc[0][nt], 0, 0, 0);
      #pragma unroll
      for (int nt = 0; nt < 4; ++nt)
        acc[1][nt] = __builtin_amdgcn_mfma_f32_16x16x32_bf16(af1, bfc[nt], acc[1][nt], 0, 0, 0);
      if (kt < 7) {
        #pragma unroll
        for (int nt = 0; nt < 4; ++nt) bfc[nt] = bfn[nt];
      }
    }

    // ---- issue next tile's global loads (latency hides under epilogue) ----
    if (have_next) {
      long grow = tn * BM + srow;
      bool ok = grow < N_NODES;
      const float* px = x + grow * DIM + sub * 8;
      #pragma unroll
      for (int i = 0; i < 4; ++i) {
        va[i] = ok ? *(const f32x4*)(px + i * 64) : f32x4{0.f, 0.f, 0.f, 0.f};
        vb[i] = ok ? *(const f32x4*)(px + i * 64 + 4) : f32x4{0.f, 0.f, 0.f, 0.f};
      }
      mreg = ok ? mask[grow] : 0.f;
    }

    // ---- epilogue for current tile ----
    #pragma unroll
    for (int mt = 0; mt < 2; ++mt) {
      float sxe[4], rxi[4], mke[4];
      long rows[4];
      #pragma unroll
      for (int i = 0; i < 4; ++i) {
        const int rloc = mt * 16 + q * 4 + i;       // C/D: row = 4*(lane>>4)+reg
        sxe[i] = sxl[rloc];
        rows[i] = tt * BM + rloc;
        mke[i] = mskl[rloc] * 0.6931471805599453f;  // fold ln2 into mask
        rxi[i] = __builtin_amdgcn_rcpf(1.0f - sxe[i]);  // 1-sx >= 0.18, exact enough
      }
      #pragma unroll
      for (int nt = 0; nt < 4; ++nt) {
        const int col = c0 + nt * 16 + ln;          // C/D: col = lane&15
        #pragma unroll
        for (int i = 0; i < 4; ++i) {
          float xc = acc[mt][nt][i];
          float sq = fmaxf(fmaf(-2.0f, xc, sxe[i] + scv[nt]), 0.0f);
          float z = fmaf(sq * rxi[i], rc2v[nt], 1.0f);
          z = fmaxf(z, 1.0f + 1e-7f);
          float t2 = z + sqrtf(fmaf(z, z, -1.0f));
          float o = __log2f(t2) * mke[i];
          if (rows[i] < N_NODES) out1[rows[i] * CDIM + col] = o;
          pc[nt] += o;
        }
      }
    }

    __syncthreads();               // all waves done reading ab/sxl for tile tt
    if (have_next) {
      float ss = 0.f;
      #pragma unroll
      for (int i = 0; i < 4; ++i) {
        ss = fmaf(va[i].x, va[i].x, ss); ss = fmaf(va[i].y, va[i].y, ss);
        ss = fmaf(va[i].z, va[i].z, ss); ss = fmaf(va[i].w, va[i].w, ss);
        ss = fmaf(vb[i].x, vb[i].x, ss); ss = fmaf(vb[i].y, vb[i].y, ss);
        ss = fmaf(vb[i].z, vb[i].z, ss); ss = fmaf(vb[i].w, vb[i].w, ss);
        u16x8 bpk;
        bpk[0] = f2bf(va[i].x); bpk[1] = f2bf(va[i].y);
        bpk[2] = f2bf(va[i].z); bpk[3] = f2bf(va[i].w);
        bpk[4] = f2bf(vb[i].x); bpk[5] = f2bf(vb[i].y);
        bpk[6] = f2bf(vb[i].z); bpk[7] = f2bf(vb[i].w);
        const int kf = sub + 8 * i;
        *(u16x8*)(ab + (((kf * BM + srow) * 8) ^ (sub << 3))) = bpk;
      }
      ss += __shfl_xor(ss, 1);
      ss += __shfl_xor(ss, 2);
      ss += __shfl_xor(ss, 4);
      if (sub == 0) { sxl[srow] = ss; mskl[srow] = mreg; }
      __syncthreads();             // ab ready for next iteration
    }
  }

  // ---- one atomic pass per block into a replicated accumulator ----
  float* gr = gaccR + (size_t)(bid & 63) * CDIM;
  #pragma unroll
  for (int nt = 0; nt < 4; ++nt) {
    float s = pc[nt];
    s += __shfl_xor(s, 16);
    s += __shfl_xor(s, 32);
    if (lane < 16) atomicAdd(gr + c0 + nt * 16 + ln, s);
  }
}

__global__ void cd_final(const float* __restrict__ gaccR, const float* __restrict__ msum,
                         float* __restrict__ out0) {
  int t = threadIdx.x;
  float s = 0.f;
  for (int r = 0; r < 64; ++r) s += gaccR[r * CDIM + t];
  out0[t] = s / msum[0];
}

extern "C" void kernel_launch(void* const* d_in, const int* in_sizes, int n_in,
                              void* d_out, int out_size, void* d_ws, size_t ws_size,
                              hipStream_t stream) {
  const float* x    = (const float*)d_in[0];   // [150000,256]
  const float* mask = (const float*)d_in[1];   // [150000,1]
  const float* cw   = (const float*)d_in[2];   // [256,256]
  float* out = (float*)d_out;                  // [256] ++ [150000*256]
  char* ws = (char*)d_ws;
  unsigned short* cb = (unsigned short*)(ws + WS_CB);
  float* sc    = (float*)(ws + WS_SC);
  float* rc2   = (float*)(ws + WS_RC2);
  float* msum  = (float*)(ws + WS_MSUM);
  float* gaccR = (float*)(ws + WS_GACCR);

  hipMemsetAsync(ws + WS_ZERO_FROM, 0, WS_ZERO_LEN, stream);
  cd_prep<<<320, 256, 0, stream>>>(cw, mask, cb, sc, rc2, msum);
  cd_main<<<GRID, 256, 0, stream>>>(x, mask, cb, sc, rc2, gaccR, out + 256);
  cd_final<<<1, 256, 0, stream>>>(gaccR, msum, out);
}